// Round 10
// baseline (149.310 us; speedup 1.0000x reference)
//
#include <hip/hip_runtime.h>

#define BDIM 256
constexpr int Bn = 16, Cn = 4, Hn = 512, Wn = 512;
constexpr int SL   = Bn * Cn;          // 64 slices
constexpr int WPR  = Wn / 4;           // 128 int4/float4 words per row
constexpr int RPW  = 4;                // rows per wave
constexpr int RPB  = 16;               // rows per block (4 waves x 4 rows)
constexpr int CPB  = Hn / RPB;         // 32 chunks per slice
constexpr int NBLK = SL * CPB;         // 2048 blocks
constexpr float NTOT = 16777216.0f;    // B*C*H*W
constexpr float SMOOTHF = 0.0001f;

// ws layout (floats): [0..63] inter/slice, [64..127] i/slice, [128..191] j/slice,
// [192..255] ce/slice, [256..319] ed/slice, [320..383] (uint) per-slice counters,
// [384] (uint) global slice counter. 1540 B, zeroed by memsetAsync per iteration.

__device__ __forceinline__ float wave_reduce(float v) {
#pragma unroll
    for (int off = 32; off > 0; off >>= 1) v += __shfl_down(v, off);
    return v;
}

typedef float vf4 __attribute__((ext_vector_type(4)));

__device__ __forceinline__ float4 ldnt_f4(const float4* p) {
    vf4 v = __builtin_nontemporal_load((const vf4*)p);
    return make_float4(v.x, v.y, v.z, v.w);
}

__device__ __forceinline__ float aload(const float* p) {
    return __hip_atomic_load(p, __ATOMIC_RELAXED, __HIP_MEMORY_SCOPE_AGENT);
}

__device__ __forceinline__ unsigned pack4(int4 c) {
    return (unsigned)c.x | ((unsigned)c.y << 8) |
           ((unsigned)c.z << 16) | ((unsigned)c.w << 24);
}

// Round-8 body (cached gt / nt cmap split: 146.1 -> 134.4us) + FENCE-FREE
// single-kernel finish. Round-2's fusion disaster was the per-block
// __threadfence + ACQ_REL (agent-scope release = L2 writeback-inv x2048,
// WRITE_SIZE 214 MB). This version uses ONLY relaxed device-scope atomics:
//  - plain atomicAdd for partials (device-scope, relaxed, no cache flush);
//  - ordering: the atomics' RETURNED values are consumed by an asm use ->
//    compiler emits s_waitcnt vmcnt(0) -> RMWs are performed at the
//    coherence point before the counter bump;
//  - two-level completion counters (32 bumps/slice-counter, 64 on global)
//    so no address sees 2048 serialized RMWs;
//  - finish reads via relaxed agent-scope atomic loads (coherence point).
// Tripwire: if WRITE_SIZE balloons again, this theory is wrong -> revert.
__global__ __launch_bounds__(BDIM, 4) void seg_main(const float4* __restrict__ cmap,
                                                    const int4* __restrict__ gt,
                                                    float* __restrict__ ws,
                                                    float* __restrict__ out) {
    __shared__ float sm[5][4];
    __shared__ unsigned lastflag;

    const int tid   = threadIdx.x;
    const int lane  = tid & 63;
    const int wave  = tid >> 6;
    const int slice = blockIdx.x >> 5;        // / CPB
    const int chunk = blockIdx.x & (CPB - 1);
    const int R0    = chunk * RPB + wave * RPW;

    const float4* cm = cmap + slice * (Hn * WPR);
    const int4*   gs = gt   + slice * (Hn * WPR);
    const int wi = 2 * lane;                  // this lane: words wi, wi+1 (elems 8l..8l+7)

    // ---- prologue: issue all 20 loads back-to-back ----
    // gt rows staged: g[2j],g[2j+1] <-> gt row R0-1+j, j = 0..5   (CACHED)
    // cmap rows xf[2k],xf[2k+1] <-> row R0+k, k = 0..3            (NT)
    int4 g[12];
    float4 xf[8];
    {
        const int rm = max(R0 - 1, 0);
        g[0]  = gs[rm * WPR + wi];
        g[1]  = gs[rm * WPR + wi + 1];
        g[2]  = gs[R0 * WPR + wi];
        g[3]  = gs[R0 * WPR + wi + 1];
        g[4]  = gs[(R0 + 1) * WPR + wi];      // R0+1 <= 509, valid
        g[5]  = gs[(R0 + 1) * WPR + wi + 1];
        xf[0] = ldnt_f4(cm + R0 * WPR + wi);
        xf[1] = ldnt_f4(cm + R0 * WPR + wi + 1);
        g[6]  = gs[(R0 + 2) * WPR + wi];      // <= 510
        g[7]  = gs[(R0 + 2) * WPR + wi + 1];
        xf[2] = ldnt_f4(cm + (R0 + 1) * WPR + wi);
        xf[3] = ldnt_f4(cm + (R0 + 1) * WPR + wi + 1);
        g[8]  = gs[(R0 + 3) * WPR + wi];      // <= 511
        g[9]  = gs[(R0 + 3) * WPR + wi + 1];
        xf[4] = ldnt_f4(cm + (R0 + 2) * WPR + wi);
        xf[5] = ldnt_f4(cm + (R0 + 2) * WPR + wi + 1);
        const int rl = min(R0 + 4, Hn - 1);
        g[10] = gs[rl * WPR + wi];
        g[11] = gs[rl * WPR + wi + 1];
        xf[6] = ldnt_f4(cm + (R0 + 3) * WPR + wi);
        xf[7] = ldnt_f4(cm + (R0 + 3) * WPR + wi + 1);
    }
    // Fence: loads cannot sink past a memory-clobber asm; compute cannot be
    // scheduled above sched_barrier(0). Forces the load burst to issue here.
    asm volatile("" ::: "memory");
    __builtin_amdgcn_sched_barrier(0);

    // pack first three gt rows (up / center / down for output row R0)
    unsigned u0 = pack4(g[0]), u1 = pack4(g[1]);
    if (R0 == 0) { u0 = 0u; u1 = 0u; }
    unsigned c0 = pack4(g[2]), c1 = pack4(g[3]);
    unsigned d0 = pack4(g[4]), d1 = pack4(g[5]);

    float cesum = 0.f, cxy = 0.f, ed = 0.f, inter = 0.f, jsum = 0.f;
    int icnt = 0;

#pragma unroll
    for (int k = 0; k < RPW; ++k) {
        // horizontal neighbors: intra-wave shfl; lane edges are the zero pad
        unsigned pw = __shfl_up(c1, 1);   if (lane == 0)  pw = 0u;
        unsigned nw = __shfl_down(c0, 1); if (lane == 63) nw = 0u;

        const unsigned l0 = (c0 << 8) | (pw >> 24);
        const unsigned r0 = (c0 >> 8) | ((c1 & 0xffu) << 24);
        const unsigned l1 = (c1 << 8) | (c0 >> 24);
        const unsigned r1 = (c1 >> 8) | (nw << 24);

        // bytes are 0/1: dilation = bitwise OR, erosion = bitwise AND
        const unsigned ew0 = (c0 | u0 | d0 | l0 | r0) & ~(c0 & u0 & d0 & l0 & r0);
        const unsigned ew1 = (c1 | u1 | d1 | l1 | r1) & ~(c1 & u1 & d1 & l1 & r1);
        icnt += __popc(c0) + __popc(c1);

        const float4 x0 = xf[2 * k];
        const float4 x1 = xf[2 * k + 1];
        const float xs[8] = {x0.x, x0.y, x0.z, x0.w, x1.x, x1.y, x1.z, x1.w};
#pragma unroll
        for (int e = 0; e < 8; ++e) {
            const unsigned cw = (e < 4) ? c0 : c1;
            const unsigned ew = (e < 4) ? ew0 : ew1;
            const int sh = 8 * (e & 3);
            const float xv = xs[e];
            const float t  = __expf(-fabsf(xv));            // exp(-|x|)
            const float u  = 1.f + t;
            const float sp = fmaxf(xv, 0.f) + __logf(u);    // softplus = logaddexp(0,x)
            const float rc = __builtin_amdgcn_rcpf(u);
            const float pred = (xv >= 0.f) ? rc : t * rc;   // sigmoid(x)
            const float yf = (float)((cw >> sh) & 1u);
            const float eb = (float)((ew >> sh) & 1u);

            cesum += sp;
            cxy   = fmaf(yf, xv, cxy);                      // ce = cesum - cxy
            inter = fmaf(yf, pred, inter);
            jsum += pred;
            ed    = fmaf(eb, fminf(sp, 100.f), ed);         // edge loss term
        }

        // roll vertical window; pack next down-row (gt row R0+k+2)
        if (k < RPW - 1) {
            u0 = c0; u1 = c1; c0 = d0; c1 = d1;
            unsigned t0 = pack4(g[2 * k + 6]), t1 = pack4(g[2 * k + 7]);
            if (R0 + k + 2 >= Hn) { t0 = 0u; t1 = 0u; }
            d0 = t0; d1 = t1;
        }
    }

    // ---- block reduction ----
    const float v0 = wave_reduce(cesum - cxy);
    const float v1 = wave_reduce(ed);
    const float v2 = wave_reduce(inter);
    const float v3 = wave_reduce((float)icnt);
    const float v4 = wave_reduce(jsum);
    if (lane == 0) {
        sm[0][wave] = v0; sm[1][wave] = v1; sm[2][wave] = v2;
        sm[3][wave] = v3; sm[4][wave] = v4;
    }
    __syncthreads();

    // ---- relaxed device-scope accumulation + two-level completion ----
    if (tid == 0) {
        const float bce = sm[0][0] + sm[0][1] + sm[0][2] + sm[0][3];
        const float bed = sm[1][0] + sm[1][1] + sm[1][2] + sm[1][3];
        const float bin = sm[2][0] + sm[2][1] + sm[2][2] + sm[2][3];
        const float bis = sm[3][0] + sm[3][1] + sm[3][2] + sm[3][3];
        const float bjs = sm[4][0] + sm[4][1] + sm[4][2] + sm[4][3];
        const float o0 = atomicAdd(&ws[slice],        bin);
        const float o1 = atomicAdd(&ws[64  + slice],  bis);
        const float o2 = atomicAdd(&ws[128 + slice],  bjs);
        const float o3 = atomicAdd(&ws[192 + slice],  bce);
        const float o4 = atomicAdd(&ws[256 + slice],  bed);
        // Consuming the returns forces s_waitcnt vmcnt(0): the RMWs are
        // PERFORMED at the coherence point before the counter bump below.
        asm volatile("" :: "v"(o0), "v"(o1), "v"(o2), "v"(o3), "v"(o4));
        unsigned done = 0u;
        unsigned* ctr = (unsigned*)ws;
        const unsigned oc = atomicAdd(ctr + 320 + slice, 1u);
        if (oc == (unsigned)(CPB - 1)) {               // slice complete
            const unsigned og = atomicAdd(ctr + 384, 1u);
            done = (og == (unsigned)(SL - 1)) ? 1u : 0u;
        }
        lastflag = done;
    }
    __syncthreads();

    if (lastflag && wave == 0) {              // globally-last block finishes
        const float in_s = aload(&ws[lane]);
        const float i_s  = aload(&ws[64  + lane]);
        const float j_s  = aload(&ws[128 + lane]);
        const float ce_s = aload(&ws[192 + lane]);
        const float ed_s = aload(&ws[256 + lane]);
        const float score = (2.f * in_s + SMOOTHF) / (i_s + j_s + SMOOTHF);
        float dice = (1.f - score) * (1.f / (float)Bn);   // mean over batch
        dice = wave_reduce(dice);                         // sum over 64 slices
        const float ce = wave_reduce(ce_s);
        const float ed2 = wave_reduce(ed_s);
        if (lane == 0)
            out[0] = (ce + ed2) * (1.f / NTOT) + dice;
    }
}

extern "C" void kernel_launch(void* const* d_in, const int* in_sizes, int n_in,
                              void* d_out, int out_size, void* d_ws, size_t ws_size,
                              hipStream_t stream) {
    const float4* cmap = (const float4*)d_in[0];
    const int4*   gt   = (const int4*)d_in[1];
    float* ws = (float*)d_ws;
    hipMemsetAsync(ws, 0, 385 * sizeof(float), stream);   // 1540 B header
    seg_main<<<NBLK, BDIM, 0, stream>>>(cmap, gt, ws, (float*)d_out);
}

// Round 11
// 138.225 us; speedup vs baseline: 1.0802x; 1.0802x over previous
//
#include <hip/hip_runtime.h>

#define BDIM 256
constexpr int Bn = 16, Cn = 4, Hn = 512, Wn = 512;
constexpr int SL   = Bn * Cn;          // 64 slices
constexpr int WPR  = Wn / 4;           // 128 int4/float4 words per row
constexpr int RPW  = 4;                // rows per wave
constexpr int RPB  = 16;               // rows per block (4 waves x 4 rows)
constexpr int CPB  = Hn / RPB;         // 32 chunks per slice
constexpr int NBLK = SL * CPB;         // 2048 blocks (divisible by 8 -> bijective swizzle)
constexpr float NTOT = 16777216.0f;    // B*C*H*W
constexpr float SMOOTHF = 0.0001f;

__device__ __forceinline__ float wave_reduce(float v) {
#pragma unroll
    for (int off = 32; off > 0; off >>= 1) v += __shfl_down(v, off);
    return v;
}

// Round-7/8 findings: the 1.6-1.7 TB/s fetch pin of rounds 1-6 was the mixed
// L3-hit/HBM-miss stream. Split fixed it (134.4us best): cmap (64 MB, zero
// reuse) is NT -> pure HBM stream, no L3 pollution; gt (64 MB unique, 1.5x
// read due to halo) stays CACHED so halo re-reads hit L2/L3.
// Round-10 finding: single-kernel fusion regressed (atomic tail + 40us-class
// memset dispatch) -- two-kernel fence-free structure is final.
typedef float vf4 __attribute__((ext_vector_type(4)));

__device__ __forceinline__ float4 ldnt_f4(const float4* p) {
    vf4 v = __builtin_nontemporal_load((const vf4*)p);
    return make_float4(v.x, v.y, v.z, v.w);
}

__device__ __forceinline__ unsigned pack4(int4 c) {
    return (unsigned)c.x | ((unsigned)c.y << 8) |
           ((unsigned)c.z << 16) | ((unsigned)c.w << 24);
}

// Deep-prologue streaming design (round-8 body, 134.4us) + XCD-aware block
// swizzle: consecutive logical block ids (same slice, adjacent chunks) land
// on the SAME XCD, so the cached-gt halo rows shared between vertical
// neighbors hit the local 4 MB L2 instead of crossing to L3.
// NO device-scope fences (round 2: per-block agent-scope fence = L2 flush,
// WRITE_SIZE 214 MB, 5x regression).
__global__ __launch_bounds__(BDIM, 4) void seg_main(const float4* __restrict__ cmap,
                                                    const int4* __restrict__ gt,
                                                    float* __restrict__ ws) {
    __shared__ float sm[5][4];

    const int tid   = threadIdx.x;
    const int lane  = tid & 63;
    const int wave  = tid >> 6;
    // bijective XCD swizzle (NBLK % 8 == 0): hardware round-robins
    // consecutive blockIdx across 8 XCDs; after this remap each XCD gets a
    // contiguous run of 256 logical ids = 8 whole slices.
    const int swz   = (blockIdx.x & 7) * (NBLK / 8) + (blockIdx.x >> 3);
    const int slice = swz >> 5;               // / CPB
    const int chunk = swz & (CPB - 1);
    const int R0    = chunk * RPB + wave * RPW;

    const float4* cm = cmap + slice * (Hn * WPR);
    const int4*   gs = gt   + slice * (Hn * WPR);
    const int wi = 2 * lane;                  // this lane: words wi, wi+1 (elems 8l..8l+7)

    // ---- prologue: issue all 20 loads back-to-back ----
    // gt rows staged: g[2j],g[2j+1] <-> gt row R0-1+j, j = 0..5   (CACHED)
    // cmap rows xf[2k],xf[2k+1] <-> row R0+k, k = 0..3            (NT)
    int4 g[12];
    float4 xf[8];
    {
        const int rm = max(R0 - 1, 0);
        g[0]  = gs[rm * WPR + wi];
        g[1]  = gs[rm * WPR + wi + 1];
        g[2]  = gs[R0 * WPR + wi];
        g[3]  = gs[R0 * WPR + wi + 1];
        g[4]  = gs[(R0 + 1) * WPR + wi];      // R0+1 <= 509, valid
        g[5]  = gs[(R0 + 1) * WPR + wi + 1];
        xf[0] = ldnt_f4(cm + R0 * WPR + wi);
        xf[1] = ldnt_f4(cm + R0 * WPR + wi + 1);
        g[6]  = gs[(R0 + 2) * WPR + wi];      // <= 510
        g[7]  = gs[(R0 + 2) * WPR + wi + 1];
        xf[2] = ldnt_f4(cm + (R0 + 1) * WPR + wi);
        xf[3] = ldnt_f4(cm + (R0 + 1) * WPR + wi + 1);
        g[8]  = gs[(R0 + 3) * WPR + wi];      // <= 511
        g[9]  = gs[(R0 + 3) * WPR + wi + 1];
        xf[4] = ldnt_f4(cm + (R0 + 2) * WPR + wi);
        xf[5] = ldnt_f4(cm + (R0 + 2) * WPR + wi + 1);
        const int rl = min(R0 + 4, Hn - 1);
        g[10] = gs[rl * WPR + wi];
        g[11] = gs[rl * WPR + wi + 1];
        xf[6] = ldnt_f4(cm + (R0 + 3) * WPR + wi);
        xf[7] = ldnt_f4(cm + (R0 + 3) * WPR + wi + 1);
    }
    // Fence: loads cannot sink past a memory-clobber asm; compute cannot be
    // scheduled above sched_barrier(0). Forces the load burst to issue here.
    asm volatile("" ::: "memory");
    __builtin_amdgcn_sched_barrier(0);

    // pack first three gt rows (up / center / down for output row R0)
    unsigned u0 = pack4(g[0]), u1 = pack4(g[1]);
    if (R0 == 0) { u0 = 0u; u1 = 0u; }
    unsigned c0 = pack4(g[2]), c1 = pack4(g[3]);
    unsigned d0 = pack4(g[4]), d1 = pack4(g[5]);

    float cesum = 0.f, cxy = 0.f, ed = 0.f, inter = 0.f, jsum = 0.f;
    int icnt = 0;

#pragma unroll
    for (int k = 0; k < RPW; ++k) {
        // horizontal neighbors: intra-wave shfl; lane edges are the zero pad
        unsigned pw = __shfl_up(c1, 1);   if (lane == 0)  pw = 0u;
        unsigned nw = __shfl_down(c0, 1); if (lane == 63) nw = 0u;

        const unsigned l0 = (c0 << 8) | (pw >> 24);
        const unsigned r0 = (c0 >> 8) | ((c1 & 0xffu) << 24);
        const unsigned l1 = (c1 << 8) | (c0 >> 24);
        const unsigned r1 = (c1 >> 8) | (nw << 24);

        // bytes are 0/1: dilation = bitwise OR, erosion = bitwise AND
        const unsigned ew0 = (c0 | u0 | d0 | l0 | r0) & ~(c0 & u0 & d0 & l0 & r0);
        const unsigned ew1 = (c1 | u1 | d1 | l1 | r1) & ~(c1 & u1 & d1 & l1 & r1);
        icnt += __popc(c0) + __popc(c1);

        const float4 x0 = xf[2 * k];
        const float4 x1 = xf[2 * k + 1];
        const float xs[8] = {x0.x, x0.y, x0.z, x0.w, x1.x, x1.y, x1.z, x1.w};
#pragma unroll
        for (int e = 0; e < 8; ++e) {
            const unsigned cw = (e < 4) ? c0 : c1;
            const unsigned ew = (e < 4) ? ew0 : ew1;
            const int sh = 8 * (e & 3);
            const float xv = xs[e];
            const float t  = __expf(-fabsf(xv));            // exp(-|x|)
            const float u  = 1.f + t;
            const float sp = fmaxf(xv, 0.f) + __logf(u);    // softplus = logaddexp(0,x)
            const float rc = __builtin_amdgcn_rcpf(u);
            const float pred = (xv >= 0.f) ? rc : t * rc;   // sigmoid(x)
            const float yf = (float)((cw >> sh) & 1u);
            const float eb = (float)((ew >> sh) & 1u);

            cesum += sp;
            cxy   = fmaf(yf, xv, cxy);                      // ce = cesum - cxy
            inter = fmaf(yf, pred, inter);
            jsum += pred;
            ed    = fmaf(eb, fminf(sp, 100.f), ed);         // edge loss term
        }

        // roll vertical window; pack next down-row (gt row R0+k+2)
        if (k < RPW - 1) {
            u0 = c0; u1 = c1; c0 = d0; c1 = d1;
            unsigned t0 = pack4(g[2 * k + 6]), t1 = pack4(g[2 * k + 7]);
            if (R0 + k + 2 >= Hn) { t0 = 0u; t1 = 0u; }
            d0 = t0; d1 = t1;
        }
    }

    // ---- block reduction, one write per partial, no atomics ----
    const float v0 = wave_reduce(cesum - cxy);
    const float v1 = wave_reduce(ed);
    const float v2 = wave_reduce(inter);
    const float v3 = wave_reduce((float)icnt);
    const float v4 = wave_reduce(jsum);
    if (lane == 0) {
        sm[0][wave] = v0; sm[1][wave] = v1; sm[2][wave] = v2;
        sm[3][wave] = v3; sm[4][wave] = v4;
    }
    __syncthreads();
    if (tid < 5)   // index by LOGICAL id so seg_finish's slice mapping holds
        ws[tid * NBLK + swz] = sm[tid][0] + sm[tid][1] + sm[tid][2] + sm[tid][3];
}

__global__ void seg_finish(const float* __restrict__ ws, float* __restrict__ out) {
    const int t = threadIdx.x;                // 64 threads, one per (b,c) slice
    float ce = 0.f, ed = 0.f, inter = 0.f, is = 0.f, js = 0.f;
#pragma unroll 8
    for (int i = 0; i < CPB; ++i) {
        const int b = t * CPB + i;
        ce    += ws[0 * NBLK + b];
        ed    += ws[1 * NBLK + b];
        inter += ws[2 * NBLK + b];
        is    += ws[3 * NBLK + b];
        js    += ws[4 * NBLK + b];
    }
    const float score = (2.f * inter + SMOOTHF) / (is + js + SMOOTHF);
    float dice = (1.f - score) * (1.f / (float)Bn);   // mean over batch
    dice = wave_reduce(dice);                         // sum over classes (64 slices)
    ce = wave_reduce(ce);
    ed = wave_reduce(ed);
    if (t == 0)
        out[0] = ce * (1.f / NTOT) + ed * (1.f / NTOT) + dice;
}

extern "C" void kernel_launch(void* const* d_in, const int* in_sizes, int n_in,
                              void* d_out, int out_size, void* d_ws, size_t ws_size,
                              hipStream_t stream) {
    const float4* cmap = (const float4*)d_in[0];
    const int4*   gt   = (const int4*)d_in[1];
    float* ws = (float*)d_ws;                 // 5 * 2048 floats, fully rewritten
    seg_main<<<NBLK, BDIM, 0, stream>>>(cmap, gt, ws);
    seg_finish<<<1, 64, 0, stream>>>(ws, (float*)d_out);
}

// Round 12
// 132.119 us; speedup vs baseline: 1.1301x; 1.0462x over previous
//
#include <hip/hip_runtime.h>

#define BDIM 256
constexpr int Bn = 16, Cn = 4, Hn = 512, Wn = 512;
constexpr int SL   = Bn * Cn;          // 64 slices
constexpr int WPR  = Wn / 4;           // 128 int4/float4 words per row
constexpr int RPW  = 4;                // rows per wave
constexpr int RPB  = 16;               // rows per block (4 waves x 4 rows)
constexpr int CPB  = Hn / RPB;         // 32 chunks per slice
constexpr int NBLK = SL * CPB;         // 2048 blocks
constexpr float NTOT = 16777216.0f;    // B*C*H*W
constexpr float SMOOTHF = 0.0001f;

__device__ __forceinline__ float wave_reduce(float v) {
#pragma unroll
    for (int off = 32; off > 0; off >>= 1) v += __shfl_down(v, off);
    return v;
}

// Settled findings (rounds 1-11):
//  - rounds 1-6: fetch pinned at 1.6-1.7 TB/s for ANY schedule when the
//    read stream mixes L3 hits and HBM misses; chip does 6.7 TB/s pure.
//  - round 7/8: fix = stream split. cmap (64 MB, zero reuse) NT -> pure HBM
//    stream, no L3 allocation; gt (64 MB unique, 1.5x halo re-read) CACHED
//    so halo hits L2/L3. 146.1 -> 134.4us.
//  - round 2/10: fusion dead twice (ACQ_REL = L2 flush; relaxed-atomic tail
//    + memset dispatch also net-negative). Two-kernel structure is final.
//  - round 11: XCD swizzle regressed (-3.8us): negligible inter-block gt
//    reuse, and the remap perturbs the nt cmap stream's dispatch locality.
typedef float vf4 __attribute__((ext_vector_type(4)));

__device__ __forceinline__ float4 ldnt_f4(const float4* p) {
    vf4 v = __builtin_nontemporal_load((const vf4*)p);
    return make_float4(v.x, v.y, v.z, v.w);
}

__device__ __forceinline__ unsigned pack4(int4 c) {
    return (unsigned)c.x | ((unsigned)c.y << 8) |
           ((unsigned)c.z << 16) | ((unsigned)c.w << 24);
}

// Deep-prologue streaming design (round-8 body, best measured 134.4us).
// 20 loads issued back-to-back, compiler fence pins issue order, counted
// vmcnt waits. NO device-scope fences; NO swizzle.
__global__ __launch_bounds__(BDIM, 4) void seg_main(const float4* __restrict__ cmap,
                                                    const int4* __restrict__ gt,
                                                    float* __restrict__ ws) {
    __shared__ float sm[5][4];

    const int tid   = threadIdx.x;
    const int lane  = tid & 63;
    const int wave  = tid >> 6;
    const int slice = blockIdx.x >> 5;        // / CPB
    const int chunk = blockIdx.x & (CPB - 1);
    const int R0    = chunk * RPB + wave * RPW;

    const float4* cm = cmap + slice * (Hn * WPR);
    const int4*   gs = gt   + slice * (Hn * WPR);
    const int wi = 2 * lane;                  // this lane: words wi, wi+1 (elems 8l..8l+7)

    // ---- prologue: issue all 20 loads back-to-back ----
    // gt rows staged: g[2j],g[2j+1] <-> gt row R0-1+j, j = 0..5   (CACHED)
    // cmap rows xf[2k],xf[2k+1] <-> row R0+k, k = 0..3            (NT)
    int4 g[12];
    float4 xf[8];
    {
        const int rm = max(R0 - 1, 0);
        g[0]  = gs[rm * WPR + wi];
        g[1]  = gs[rm * WPR + wi + 1];
        g[2]  = gs[R0 * WPR + wi];
        g[3]  = gs[R0 * WPR + wi + 1];
        g[4]  = gs[(R0 + 1) * WPR + wi];      // R0+1 <= 509, valid
        g[5]  = gs[(R0 + 1) * WPR + wi + 1];
        xf[0] = ldnt_f4(cm + R0 * WPR + wi);
        xf[1] = ldnt_f4(cm + R0 * WPR + wi + 1);
        g[6]  = gs[(R0 + 2) * WPR + wi];      // <= 510
        g[7]  = gs[(R0 + 2) * WPR + wi + 1];
        xf[2] = ldnt_f4(cm + (R0 + 1) * WPR + wi);
        xf[3] = ldnt_f4(cm + (R0 + 1) * WPR + wi + 1);
        g[8]  = gs[(R0 + 3) * WPR + wi];      // <= 511
        g[9]  = gs[(R0 + 3) * WPR + wi + 1];
        xf[4] = ldnt_f4(cm + (R0 + 2) * WPR + wi);
        xf[5] = ldnt_f4(cm + (R0 + 2) * WPR + wi + 1);
        const int rl = min(R0 + 4, Hn - 1);
        g[10] = gs[rl * WPR + wi];
        g[11] = gs[rl * WPR + wi + 1];
        xf[6] = ldnt_f4(cm + (R0 + 3) * WPR + wi);
        xf[7] = ldnt_f4(cm + (R0 + 3) * WPR + wi + 1);
    }
    // Fence: loads cannot sink past a memory-clobber asm; compute cannot be
    // scheduled above sched_barrier(0). Forces the load burst to issue here.
    asm volatile("" ::: "memory");
    __builtin_amdgcn_sched_barrier(0);

    // pack first three gt rows (up / center / down for output row R0)
    unsigned u0 = pack4(g[0]), u1 = pack4(g[1]);
    if (R0 == 0) { u0 = 0u; u1 = 0u; }
    unsigned c0 = pack4(g[2]), c1 = pack4(g[3]);
    unsigned d0 = pack4(g[4]), d1 = pack4(g[5]);

    float cesum = 0.f, cxy = 0.f, ed = 0.f, inter = 0.f, jsum = 0.f;
    int icnt = 0;

#pragma unroll
    for (int k = 0; k < RPW; ++k) {
        // horizontal neighbors: intra-wave shfl; lane edges are the zero pad
        unsigned pw = __shfl_up(c1, 1);   if (lane == 0)  pw = 0u;
        unsigned nw = __shfl_down(c0, 1); if (lane == 63) nw = 0u;

        const unsigned l0 = (c0 << 8) | (pw >> 24);
        const unsigned r0 = (c0 >> 8) | ((c1 & 0xffu) << 24);
        const unsigned l1 = (c1 << 8) | (c0 >> 24);
        const unsigned r1 = (c1 >> 8) | (nw << 24);

        // bytes are 0/1: dilation = bitwise OR, erosion = bitwise AND
        const unsigned ew0 = (c0 | u0 | d0 | l0 | r0) & ~(c0 & u0 & d0 & l0 & r0);
        const unsigned ew1 = (c1 | u1 | d1 | l1 | r1) & ~(c1 & u1 & d1 & l1 & r1);
        icnt += __popc(c0) + __popc(c1);

        const float4 x0 = xf[2 * k];
        const float4 x1 = xf[2 * k + 1];
        const float xs[8] = {x0.x, x0.y, x0.z, x0.w, x1.x, x1.y, x1.z, x1.w};
#pragma unroll
        for (int e = 0; e < 8; ++e) {
            const unsigned cw = (e < 4) ? c0 : c1;
            const unsigned ew = (e < 4) ? ew0 : ew1;
            const int sh = 8 * (e & 3);
            const float xv = xs[e];
            const float t  = __expf(-fabsf(xv));            // exp(-|x|)
            const float u  = 1.f + t;
            const float sp = fmaxf(xv, 0.f) + __logf(u);    // softplus = logaddexp(0,x)
            const float rc = __builtin_amdgcn_rcpf(u);
            const float pred = (xv >= 0.f) ? rc : t * rc;   // sigmoid(x)
            const float yf = (float)((cw >> sh) & 1u);
            const float eb = (float)((ew >> sh) & 1u);

            cesum += sp;
            cxy   = fmaf(yf, xv, cxy);                      // ce = cesum - cxy
            inter = fmaf(yf, pred, inter);
            jsum += pred;
            ed    = fmaf(eb, fminf(sp, 100.f), ed);         // edge loss term
        }

        // roll vertical window; pack next down-row (gt row R0+k+2)
        if (k < RPW - 1) {
            u0 = c0; u1 = c1; c0 = d0; c1 = d1;
            unsigned t0 = pack4(g[2 * k + 6]), t1 = pack4(g[2 * k + 7]);
            if (R0 + k + 2 >= Hn) { t0 = 0u; t1 = 0u; }
            d0 = t0; d1 = t1;
        }
    }

    // ---- block reduction, one write per partial, no atomics ----
    const float v0 = wave_reduce(cesum - cxy);
    const float v1 = wave_reduce(ed);
    const float v2 = wave_reduce(inter);
    const float v3 = wave_reduce((float)icnt);
    const float v4 = wave_reduce(jsum);
    if (lane == 0) {
        sm[0][wave] = v0; sm[1][wave] = v1; sm[2][wave] = v2;
        sm[3][wave] = v3; sm[4][wave] = v4;
    }
    __syncthreads();
    if (tid < 5)
        ws[tid * NBLK + blockIdx.x] = sm[tid][0] + sm[tid][1] + sm[tid][2] + sm[tid][3];
}

// Vectorized finish: 256 threads, 4 per slice. Each thread: 10 independent
// float4 loads (2 per partial-array x 5 arrays), local sum, shfl_xor reduce
// over the 4-lane sub-group, per-slice dice on sub==0, wave reduce, tiny
// LDS cross-wave combine. Replaces 1 wave x 160 scalar latency-serialized
// loads (old seg_finish violated G13).
__global__ void seg_finish(const float* __restrict__ ws, float* __restrict__ out) {
    __shared__ float acc[3][4];
    const int tid   = threadIdx.x;            // 0..255
    const int lane  = tid & 63;
    const int wave  = tid >> 6;
    const int slice = tid >> 2;               // 0..63
    const int sub   = tid & 3;                // 0..3: 8 chunks each

    const float4* w4 = (const float4*)ws;     // ws: 5 arrays x 2048 floats
    float s[5];
#pragma unroll
    for (int a = 0; a < 5; ++a) {
        const int base = a * (NBLK / 4) + slice * 8 + sub * 2;
        const float4 p = w4[base];
        const float4 q = w4[base + 1];
        s[a] = ((p.x + p.y) + (p.z + p.w)) + ((q.x + q.y) + (q.z + q.w));
    }
#pragma unroll
    for (int a = 0; a < 5; ++a) {             // reduce over the 4-lane group
        s[a] += __shfl_xor(s[a], 1);
        s[a] += __shfl_xor(s[a], 2);
    }
    float ce = 0.f, ed = 0.f, dice = 0.f;
    if (sub == 0) {
        ce = s[0]; ed = s[1];
        const float score = (2.f * s[2] + SMOOTHF) / (s[3] + s[4] + SMOOTHF);
        dice = (1.f - score) * (1.f / (float)Bn);   // mean over batch
    }
    ce   = wave_reduce(ce);
    ed   = wave_reduce(ed);
    dice = wave_reduce(dice);
    if (lane == 0) { acc[0][wave] = ce; acc[1][wave] = ed; acc[2][wave] = dice; }
    __syncthreads();
    if (tid == 0) {
        const float tce = acc[0][0] + acc[0][1] + acc[0][2] + acc[0][3];
        const float ted = acc[1][0] + acc[1][1] + acc[1][2] + acc[1][3];
        const float tdi = acc[2][0] + acc[2][1] + acc[2][2] + acc[2][3];
        out[0] = (tce + ted) * (1.f / NTOT) + tdi;
    }
}

extern "C" void kernel_launch(void* const* d_in, const int* in_sizes, int n_in,
                              void* d_out, int out_size, void* d_ws, size_t ws_size,
                              hipStream_t stream) {
    const float4* cmap = (const float4*)d_in[0];
    const int4*   gt   = (const int4*)d_in[1];
    float* ws = (float*)d_ws;                 // 5 * 2048 floats, fully rewritten
    seg_main<<<NBLK, BDIM, 0, stream>>>(cmap, gt, ws);
    seg_finish<<<1, 256, 0, stream>>>(ws, (float*)d_out);
}